// Round 1
// baseline (407.398 us; speedup 1.0000x reference)
//
#include <hip/hip_runtime.h>
#include <math.h>

#define TPB 512

// Fully fused DeepSets forward: one block per batch element b.
// Phi (3->120->100->80, relu) on 128 set elements, sum-pool, Rho, Q-head, softmax.
// Activations stay in LDS; weights stream from global (L1/L2-resident, uniform
// per half-wave => broadcast). h1/h2 row strides padded to odd-multiple-of-4
// floats (124, 108) so per-lane ds_read_b128 hits the 4-way floor, not 16/32-way.
__global__ __launch_bounds__(TPB, 1)
void ds_fused(const float* __restrict__ dyn,   // [2048,128,3]
              const float* __restrict__ stat,  // [2048,3]
              const float* __restrict__ pw1, const float* __restrict__ pb1, // [120,3],[120]
              const float* __restrict__ pw2, const float* __restrict__ pb2, // [100,120],[100]
              const float* __restrict__ pw3, const float* __restrict__ pb3, // [80,100],[80]
              const float* __restrict__ rw1, const float* __restrict__ rb1, // [60,80],[60]
              const float* __restrict__ rw2, const float* __restrict__ rb2, // [60,60],[60]
              const float* __restrict__ rw3, const float* __restrict__ rb3, // [40,60],[40]
              const float* __restrict__ qw1, const float* __restrict__ qb1, // [200,43],[200]
              const float* __restrict__ qw2, const float* __restrict__ qb2, // [100,200],[100]
              const float* __restrict__ qw3, const float* __restrict__ qb3, // [3,100],[3]
              float* __restrict__ out)         // [2048,3]
{
    const int b   = blockIdx.x;
    const int tid = threadIdx.x;
    const int tx  = tid & 31;   // el-lane: els {tx, tx+32, tx+64, tx+96}
    const int ty  = tid >> 5;   // 0..15, one per half-wave (uniform weight rows)

    __shared__ __align__(16) float xs[384];          // dyn[b] flat
    __shared__ __align__(16) float h1[128 * 124];    // 120 cols, pad->124 (odd*4)
    __shared__ __align__(16) float h2[128 * 108];    // 100 cols, pad->108 (odd*4)
    __shared__ __align__(16) float pooled[80];
    __shared__ __align__(16) float r1s[64];
    __shared__ __align__(16) float r2s[64];
    __shared__ __align__(16) float xcat[48];
    __shared__ __align__(16) float q1s[200];
    __shared__ __align__(16) float q2s[104];
    __shared__ float logits[3];

    // ---- stage dyn[b] -> LDS (96 float4 = 384 floats) ----
    if (tid < 96)
        *(float4*)(xs + tid * 4) = *(const float4*)(dyn + (size_t)b * 384 + tid * 4);
    __syncthreads();

    // ---- Phi layer 1: h1[el][o] = relu(b1[o] + sum_i x[el][i] * w1[o][i]) ----
    for (int p = tid; p < 128 * 120; p += TPB) {
        int el = p / 120;
        int o  = p - el * 120;
        float v = pb1[o]
                + xs[el * 3 + 0] * pw1[o * 3 + 0]
                + xs[el * 3 + 1] * pw1[o * 3 + 1]
                + xs[el * 3 + 2] * pw1[o * 3 + 2];
        h1[el * 124 + o] = fmaxf(v, 0.0f);
    }
    __syncthreads();

    // ---- Phi layer 2: h2 = relu(h1 @ w2^T + b2)  [128x120]x[120x100] ----
    {
        float acc[4][7];
        #pragma unroll
        for (int e = 0; e < 4; ++e)
            #pragma unroll
            for (int j = 0; j < 7; ++j) acc[e][j] = 0.0f;

        for (int k = 0; k < 120; k += 4) {
            float4 hv[4];
            #pragma unroll
            for (int e = 0; e < 4; ++e)
                hv[e] = *(const float4*)(h1 + (tx + 32 * e) * 124 + k);
            #pragma unroll
            for (int j = 0; j < 7; ++j) {
                int o = ty * 7 + j; if (o > 99) o = 99;   // clamp (safe load)
                float4 wv = *(const float4*)(pw2 + o * 120 + k);
                #pragma unroll
                for (int e = 0; e < 4; ++e)
                    acc[e][j] += hv[e].x * wv.x + hv[e].y * wv.y
                               + hv[e].z * wv.z + hv[e].w * wv.w;
            }
        }
        #pragma unroll
        for (int j = 0; j < 7; ++j) {
            int o = ty * 7 + j;
            if (o < 100) {
                float bb = pb2[o];
                #pragma unroll
                for (int e = 0; e < 4; ++e)
                    h2[(tx + 32 * e) * 108 + o] = fmaxf(acc[e][j] + bb, 0.0f);
            }
        }
    }
    __syncthreads();

    // ---- Phi layer 3 + sum-pool: pooled[o] = sum_el relu(h2@w3^T + b3) ----
    {
        float acc[4][5];
        #pragma unroll
        for (int e = 0; e < 4; ++e)
            #pragma unroll
            for (int j = 0; j < 5; ++j) acc[e][j] = 0.0f;

        for (int k = 0; k < 100; k += 4) {
            float4 hv[4];
            #pragma unroll
            for (int e = 0; e < 4; ++e)
                hv[e] = *(const float4*)(h2 + (tx + 32 * e) * 108 + k);
            #pragma unroll
            for (int j = 0; j < 5; ++j) {
                int o = ty * 5 + j;                        // 16*5 = 80 exact
                float4 wv = *(const float4*)(pw3 + o * 100 + k);
                #pragma unroll
                for (int e = 0; e < 4; ++e)
                    acc[e][j] += hv[e].x * wv.x + hv[e].y * wv.y
                               + hv[e].z * wv.z + hv[e].w * wv.w;
            }
        }
        #pragma unroll
        for (int j = 0; j < 5; ++j) {
            float bb = pb3[ty * 5 + j];
            float s = fmaxf(acc[0][j] + bb, 0.0f) + fmaxf(acc[1][j] + bb, 0.0f)
                    + fmaxf(acc[2][j] + bb, 0.0f) + fmaxf(acc[3][j] + bb, 0.0f);
            #pragma unroll
            for (int d = 16; d > 0; d >>= 1) s += __shfl_down(s, d, 32);
            if (tx == 0) pooled[ty * 5 + j] = s;
        }
    }
    __syncthreads();

    // ---- Rho layer 1: 80 -> 60, relu ----
    if (tid < 60) {
        float a = rb1[tid];
        for (int k = 0; k < 80; k += 4) {
            float4 pv = *(const float4*)(pooled + k);
            float4 wv = *(const float4*)(rw1 + tid * 80 + k);
            a += pv.x * wv.x + pv.y * wv.y + pv.z * wv.z + pv.w * wv.w;
        }
        r1s[tid] = fmaxf(a, 0.0f);
    }
    __syncthreads();

    // ---- Rho layer 2: 60 -> 60, relu ----
    if (tid < 60) {
        float a = rb2[tid];
        for (int k = 0; k < 60; k += 4) {
            float4 pv = *(const float4*)(r1s + k);
            float4 wv = *(const float4*)(rw2 + tid * 60 + k);
            a += pv.x * wv.x + pv.y * wv.y + pv.z * wv.z + pv.w * wv.w;
        }
        r2s[tid] = fmaxf(a, 0.0f);
    }
    __syncthreads();

    // ---- Rho layer 3: 60 -> 40 (no relu), concat static -> xcat[43] ----
    if (tid < 40) {
        float a = rb3[tid];
        for (int k = 0; k < 60; k += 4) {
            float4 pv = *(const float4*)(r2s + k);
            float4 wv = *(const float4*)(rw3 + tid * 60 + k);
            a += pv.x * wv.x + pv.y * wv.y + pv.z * wv.z + pv.w * wv.w;
        }
        xcat[tid] = a;
    }
    if (tid >= 40 && tid < 43) xcat[tid] = stat[(size_t)b * 3 + (tid - 40)];
    __syncthreads();

    // ---- Q layer 1: 43 -> 200, relu ----
    if (tid < 200) {
        float a = qb1[tid];
        const float* w = qw1 + tid * 43;
        for (int k = 0; k < 43; ++k) a += xcat[k] * w[k];
        q1s[tid] = fmaxf(a, 0.0f);
    }
    __syncthreads();

    // ---- Q layer 2: 200 -> 100, relu ----
    if (tid < 100) {
        float a = qb2[tid];
        for (int k = 0; k < 200; k += 4) {
            float4 pv = *(const float4*)(q1s + k);
            float4 wv = *(const float4*)(qw2 + tid * 200 + k);
            a += pv.x * wv.x + pv.y * wv.y + pv.z * wv.z + pv.w * wv.w;
        }
        q2s[tid] = fmaxf(a, 0.0f);
    }
    __syncthreads();

    // ---- Q layer 3: 100 -> 3 via 3 x 32-lane partial dots ----
    if (tid < 96) {
        int o = tid >> 5, l = tid & 31;
        float a = 0.0f;
        for (int k = l; k < 100; k += 32) a += q2s[k] * qw3[o * 100 + k];
        #pragma unroll
        for (int d = 16; d > 0; d >>= 1) a += __shfl_down(a, d, 32);
        if (l == 0) logits[o] = a + qb3[o];
    }
    __syncthreads();

    // ---- softmax over 3 logits ----
    if (tid < 3) {
        float l0 = logits[0], l1 = logits[1], l2 = logits[2];
        float m  = fmaxf(l0, fmaxf(l1, l2));
        float e0 = __expf(l0 - m), e1 = __expf(l1 - m), e2 = __expf(l2 - m);
        float inv = 1.0f / (e0 + e1 + e2);
        float mine = (tid == 0) ? e0 : ((tid == 1) ? e1 : e2);
        out[(size_t)b * 3 + tid] = mine * inv;
    }
}

extern "C" void kernel_launch(void* const* d_in, const int* in_sizes, int n_in,
                              void* d_out, int out_size, void* d_ws, size_t ws_size,
                              hipStream_t stream) {
    const float* dyn  = (const float*)d_in[0];
    const float* stat = (const float*)d_in[1];
    const float* pw1  = (const float*)d_in[2];
    const float* pb1  = (const float*)d_in[3];
    const float* pw2  = (const float*)d_in[4];
    const float* pb2  = (const float*)d_in[5];
    const float* pw3  = (const float*)d_in[6];
    const float* pb3  = (const float*)d_in[7];
    const float* rw1  = (const float*)d_in[8];
    const float* rb1  = (const float*)d_in[9];
    const float* rw2  = (const float*)d_in[10];
    const float* rb2  = (const float*)d_in[11];
    const float* rw3  = (const float*)d_in[12];
    const float* rb3  = (const float*)d_in[13];
    const float* qw1  = (const float*)d_in[14];
    const float* qb1  = (const float*)d_in[15];
    const float* qw2  = (const float*)d_in[16];
    const float* qb2  = (const float*)d_in[17];
    const float* qw3  = (const float*)d_in[18];
    const float* qb3  = (const float*)d_in[19];
    float* out = (float*)d_out;

    const int B = in_sizes[0] / (128 * 3);   // 2048
    ds_fused<<<dim3(B), dim3(TPB), 0, stream>>>(
        dyn, stat, pw1, pb1, pw2, pb2, pw3, pb3,
        rw1, rb1, rw2, rb2, rw3, rb3,
        qw1, qb1, qw2, qb2, qw3, qb3, out);
}

// Round 2
// 369.110 us; speedup vs baseline: 1.1037x; 1.1037x over previous
//
#include <hip/hip_runtime.h>
#include <math.h>

#define TPB 512

typedef short s16x8 __attribute__((ext_vector_type(8)));
typedef short s16x4 __attribute__((ext_vector_type(4)));
typedef float f32x4 __attribute__((ext_vector_type(4)));

// split fp32 into bf16 hi + bf16 lo (truncation; dropped lo*lo term ~2^-16 rel)
__device__ __forceinline__ void bsplit(float x, short& hi, short& lo) {
    unsigned u  = __float_as_uint(x);
    unsigned uh = u & 0xFFFF0000u;
    hi = (short)(uh >> 16);
    float r = x - __uint_as_float(uh);
    lo = (short)(__float_as_uint(r) >> 16);
}

// d_ws layout (shorts): w2hi[112*128] @0, w2lo @14336, w3hi[80*128] @28672, w3lo @38912
__global__ void prep_w(const float* __restrict__ pw2, const float* __restrict__ pw3,
                       short* __restrict__ wb) {
    int t = blockIdx.x * 256 + threadIdx.x;
    if (t < 14336) {
        int row = t >> 7, col = t & 127;
        float v = (row < 100 && col < 120) ? pw2[row * 120 + col] : 0.f;
        short hi, lo; bsplit(v, hi, lo);
        wb[t] = hi; wb[14336 + t] = lo;
    } else if (t < 14336 + 10240) {
        int t2 = t - 14336;
        int row = t2 >> 7, col = t2 & 127;
        float v = (row < 80 && col < 100) ? pw3[row * 100 + col] : 0.f;
        short hi, lo; bsplit(v, hi, lo);
        wb[28672 + t2] = hi; wb[38912 + t2] = lo;
    }
}

// One block per batch element. Phi L2/L3 via split-bf16 MFMA (A=weights from
// global, B=h rows from swizzled LDS; C: col=el=lane&15, row=o=(lane>>4)*4+reg).
__global__ __launch_bounds__(TPB, 1)
void ds_fused(const float* __restrict__ dyn,   // [2048,128,3]
              const float* __restrict__ stat,  // [2048,3]
              const float* __restrict__ pw1, const float* __restrict__ pb1,
              const float* __restrict__ pb2, const float* __restrict__ pb3,
              const short* __restrict__ wb,    // prepped bf16 weights
              const float* __restrict__ rw1, const float* __restrict__ rb1,
              const float* __restrict__ rw2, const float* __restrict__ rb2,
              const float* __restrict__ rw3, const float* __restrict__ rb3,
              const float* __restrict__ qw1, const float* __restrict__ qb1,
              const float* __restrict__ qw2, const float* __restrict__ qb2,
              const float* __restrict__ qw3, const float* __restrict__ qb3,
              float* __restrict__ out)         // [2048,3]
{
    const int b   = blockIdx.x;
    const int tid = threadIdx.x;
    const int w   = tid >> 6;   // wave 0..7 = el-tile
    const int l   = tid & 63;
    const int l4  = l >> 4;     // 0..3
    const int ln  = l & 15;     // 0..15

    // h arrays: [128 el][128 k] bf16, row-XOR-swizzled: short-idx k ^= (el&7)<<3
    __shared__ short h1hi[128 * 128], h1lo[128 * 128];
    __shared__ short h2hi[128 * 128], h2lo[128 * 128];
    __shared__ __align__(16) float xs[384];
    __shared__ float pooled[80];
    __shared__ __align__(16) float r1s[64];
    __shared__ __align__(16) float r2s[64];
    __shared__ __align__(16) float xcat[48];
    __shared__ __align__(16) float q1s[200];
    __shared__ __align__(16) float q2s[104];
    __shared__ float logits[3];

    // ---- stage dyn[b], init pooled, pre-zero h2 pad (k 112..127) ----
    if (tid < 96)
        *(float4*)(xs + tid * 4) = *(const float4*)(dyn + (size_t)b * 384 + tid * 4);
    if (tid < 80) pooled[tid] = 0.f;
    {
        int row = tid & 127;
        int sel = tid >> 7;                 // 0..3
        int k   = 112 + 8 * (sel & 1);
        short* dst = (sel < 2) ? h2hi : h2lo;
        s16x8 z = 0;
        *(s16x8*)(dst + row * 128 + (k ^ ((row & 7) << 3))) = z;
    }
    __syncthreads();

    // ---- Phi L1 (fp32) -> h1 bf16 hi/lo; 128 el x 16 groups of 8 (g=15 zero pad) ----
    for (int i = 0; i < 4; ++i) {
        int t  = tid + TPB * i;
        int el = t >> 4, g = t & 15;
        s16x8 vh = 0, vl = 0;
        if (g < 15) {
            float x0 = xs[el * 3], x1 = xs[el * 3 + 1], x2 = xs[el * 3 + 2];
            #pragma unroll
            for (int j = 0; j < 8; ++j) {
                int o = 8 * g + j;
                float v = pb1[o] + x0 * pw1[o * 3] + x1 * pw1[o * 3 + 1] + x2 * pw1[o * 3 + 2];
                v = fmaxf(v, 0.f);
                short hi, lo; bsplit(v, hi, lo);
                vh[j] = hi; vl[j] = lo;
            }
        }
        int idx = el * 128 + ((8 * g) ^ ((el & 7) << 3));
        *(s16x8*)(h1hi + idx) = vh;
        *(s16x8*)(h1lo + idx) = vl;
    }
    __syncthreads();

    // ---- Phi L2: C'[o,el] = w2 . h1^T, split-bf16, K=128(pad) ----
    {
        const int el  = 16 * w + ln;
        const int swz = (el & 7) << 3;
        s16x8 bh[4], bl[4];
        #pragma unroll
        for (int ks = 0; ks < 4; ++ks) {
            int idx = el * 128 + ((ks * 32 + l4 * 8) ^ swz);
            bh[ks] = *(const s16x8*)(h1hi + idx);
            bl[ks] = *(const s16x8*)(h1lo + idx);
        }
        const short* w2h = wb;
        const short* w2l = wb + 14336;
        f32x4 acc[7];
        #pragma unroll
        for (int n = 0; n < 7; ++n) acc[n] = 0.f;
        #pragma unroll
        for (int ks = 0; ks < 4; ++ks) {
            #pragma unroll
            for (int n = 0; n < 7; ++n) {
                const int ro = (16 * n + ln) * 128 + ks * 32 + l4 * 8;
                s16x8 ah = *(const s16x8*)(w2h + ro);
                s16x8 al = *(const s16x8*)(w2l + ro);
                acc[n] = __builtin_amdgcn_mfma_f32_16x16x32_bf16(ah, bh[ks], acc[n], 0, 0, 0);
                acc[n] = __builtin_amdgcn_mfma_f32_16x16x32_bf16(ah, bl[ks], acc[n], 0, 0, 0);
                acc[n] = __builtin_amdgcn_mfma_f32_16x16x32_bf16(al, bh[ks], acc[n], 0, 0, 0);
            }
        }
        // epilogue: bias+relu+split -> h2[el][o] (4 consecutive o per lane)
        #pragma unroll
        for (int n = 0; n < 7; ++n) {
            int o0   = 16 * n + l4 * 4;
            int idx2 = el * 128 + (o0 ^ swz);
            if (o0 < 100) {
                float4 bb = *(const float4*)(pb2 + o0);
                float bv[4] = { bb.x, bb.y, bb.z, bb.w };
                s16x4 oh, ol;
                #pragma unroll
                for (int r = 0; r < 4; ++r) {
                    float v = fmaxf(acc[n][r] + bv[r], 0.f);
                    short hi, lo; bsplit(v, hi, lo);
                    oh[r] = hi; ol[r] = lo;
                }
                *(s16x4*)(h2hi + idx2) = oh;
                *(s16x4*)(h2lo + idx2) = ol;
            } else {
                s16x4 z = 0;
                *(s16x4*)(h2hi + idx2) = z;
                *(s16x4*)(h2lo + idx2) = z;
            }
        }
    }
    __syncthreads();

    // ---- Phi L3 + pool: C3'[o3,el] = w3 . h2^T; relu(+bias) then sum over el ----
    {
        const int el  = 16 * w + ln;
        const int swz = (el & 7) << 3;
        s16x8 bh[4], bl[4];
        #pragma unroll
        for (int ks = 0; ks < 4; ++ks) {
            int idx = el * 128 + ((ks * 32 + l4 * 8) ^ swz);
            bh[ks] = *(const s16x8*)(h2hi + idx);
            bl[ks] = *(const s16x8*)(h2lo + idx);
        }
        const short* w3h = wb + 28672;
        const short* w3l = wb + 38912;
        f32x4 acc[5];
        #pragma unroll
        for (int n = 0; n < 5; ++n) acc[n] = 0.f;
        #pragma unroll
        for (int ks = 0; ks < 4; ++ks) {
            #pragma unroll
            for (int n = 0; n < 5; ++n) {
                const int ro = (16 * n + ln) * 128 + ks * 32 + l4 * 8;
                s16x8 ah = *(const s16x8*)(w3h + ro);
                s16x8 al = *(const s16x8*)(w3l + ro);
                acc[n] = __builtin_amdgcn_mfma_f32_16x16x32_bf16(ah, bh[ks], acc[n], 0, 0, 0);
                acc[n] = __builtin_amdgcn_mfma_f32_16x16x32_bf16(ah, bl[ks], acc[n], 0, 0, 0);
                acc[n] = __builtin_amdgcn_mfma_f32_16x16x32_bf16(al, bh[ks], acc[n], 0, 0, 0);
            }
        }
        #pragma unroll
        for (int n = 0; n < 5; ++n) {
            int o0 = 16 * n + l4 * 4;
            float4 bb = *(const float4*)(pb3 + o0);
            float bv[4] = { bb.x, bb.y, bb.z, bb.w };
            #pragma unroll
            for (int r = 0; r < 4; ++r) {
                float v = fmaxf(acc[n][r] + bv[r], 0.f);
                v += __shfl_xor(v, 1);
                v += __shfl_xor(v, 2);
                v += __shfl_xor(v, 4);
                v += __shfl_xor(v, 8);
                if (ln == 0) atomicAdd(&pooled[o0 + r], v);
            }
        }
    }
    __syncthreads();

    // ---- Rho layer 1: 80 -> 60, relu ----
    if (tid < 60) {
        float a = rb1[tid];
        for (int k = 0; k < 80; k += 4) {
            float4 pv = *(const float4*)(pooled + k);
            float4 wv = *(const float4*)(rw1 + tid * 80 + k);
            a += pv.x * wv.x + pv.y * wv.y + pv.z * wv.z + pv.w * wv.w;
        }
        r1s[tid] = fmaxf(a, 0.0f);
    }
    __syncthreads();

    // ---- Rho layer 2: 60 -> 60, relu ----
    if (tid < 60) {
        float a = rb2[tid];
        for (int k = 0; k < 60; k += 4) {
            float4 pv = *(const float4*)(r1s + k);
            float4 wv = *(const float4*)(rw2 + tid * 60 + k);
            a += pv.x * wv.x + pv.y * wv.y + pv.z * wv.z + pv.w * wv.w;
        }
        r2s[tid] = fmaxf(a, 0.0f);
    }
    __syncthreads();

    // ---- Rho layer 3: 60 -> 40 (no relu), concat static ----
    if (tid < 40) {
        float a = rb3[tid];
        for (int k = 0; k < 60; k += 4) {
            float4 pv = *(const float4*)(r2s + k);
            float4 wv = *(const float4*)(rw3 + tid * 60 + k);
            a += pv.x * wv.x + pv.y * wv.y + pv.z * wv.z + pv.w * wv.w;
        }
        xcat[tid] = a;
    }
    if (tid >= 40 && tid < 43) xcat[tid] = stat[(size_t)b * 3 + (tid - 40)];
    __syncthreads();

    // ---- Q layer 1: 43 -> 200, relu ----
    if (tid < 200) {
        float a = qb1[tid];
        const float* wv = qw1 + tid * 43;
        for (int k = 0; k < 43; ++k) a += xcat[k] * wv[k];
        q1s[tid] = fmaxf(a, 0.0f);
    }
    __syncthreads();

    // ---- Q layer 2: 200 -> 100, relu ----
    if (tid < 100) {
        float a = qb2[tid];
        for (int k = 0; k < 200; k += 4) {
            float4 pv = *(const float4*)(q1s + k);
            float4 wv = *(const float4*)(qw2 + tid * 200 + k);
            a += pv.x * wv.x + pv.y * wv.y + pv.z * wv.z + pv.w * wv.w;
        }
        q2s[tid] = fmaxf(a, 0.0f);
    }
    __syncthreads();

    // ---- Q layer 3: 100 -> 3 ----
    if (tid < 96) {
        int o = tid >> 5, l2 = tid & 31;
        float a = 0.0f;
        for (int k = l2; k < 100; k += 32) a += q2s[k] * qw3[o * 100 + k];
        #pragma unroll
        for (int d = 16; d > 0; d >>= 1) a += __shfl_down(a, d, 32);
        if (l2 == 0) logits[o] = a + qb3[o];
    }
    __syncthreads();

    // ---- softmax ----
    if (tid < 3) {
        float l0 = logits[0], l1 = logits[1], l2 = logits[2];
        float m  = fmaxf(l0, fmaxf(l1, l2));
        float e0 = __expf(l0 - m), e1 = __expf(l1 - m), e2 = __expf(l2 - m);
        float inv = 1.0f / (e0 + e1 + e2);
        float mine = (tid == 0) ? e0 : ((tid == 1) ? e1 : e2);
        out[(size_t)b * 3 + tid] = mine * inv;
    }
}

extern "C" void kernel_launch(void* const* d_in, const int* in_sizes, int n_in,
                              void* d_out, int out_size, void* d_ws, size_t ws_size,
                              hipStream_t stream) {
    const float* dyn  = (const float*)d_in[0];
    const float* stat = (const float*)d_in[1];
    const float* pw1  = (const float*)d_in[2];
    const float* pb1  = (const float*)d_in[3];
    const float* pw2  = (const float*)d_in[4];
    const float* pb2  = (const float*)d_in[5];
    const float* pw3  = (const float*)d_in[6];
    const float* pb3  = (const float*)d_in[7];
    const float* rw1  = (const float*)d_in[8];
    const float* rb1  = (const float*)d_in[9];
    const float* rw2  = (const float*)d_in[10];
    const float* rb2  = (const float*)d_in[11];
    const float* rw3  = (const float*)d_in[12];
    const float* rb3  = (const float*)d_in[13];
    const float* qw1  = (const float*)d_in[14];
    const float* qb1  = (const float*)d_in[15];
    const float* qw2  = (const float*)d_in[16];
    const float* qb2  = (const float*)d_in[17];
    const float* qw3  = (const float*)d_in[18];
    const float* qb3  = (const float*)d_in[19];
    float* out = (float*)d_out;
    short* wb  = (short*)d_ws;

    const int B = in_sizes[0] / (128 * 3);   // 2048

    prep_w<<<dim3(96), dim3(256), 0, stream>>>(pw2, pw3, wb);
    ds_fused<<<dim3(B), dim3(TPB), 0, stream>>>(
        dyn, stat, pw1, pb1, pb2, pb3, wb,
        rw1, rb1, rw2, rb2, rw3, rb3,
        qw1, qb1, qw2, qb2, qw3, qb3, out);
}